// Round 14
// baseline (78.829 us; speedup 1.0000x reference)
//
#include <hip/hip_runtime.h>
#include <math.h>

#define DIM 256
#define KCODES 1024
#define NTILE 64   // 16-code tiles
#define BM 64      // rows per block (4 waves x 16 rows)
#define ESCALE 512.0f

typedef long i64;
typedef __attribute__((ext_vector_type(2))) long i64x2;
typedef __attribute__((ext_vector_type(4))) float f32x4;

// ---------------------------------------------------------------------------
// Prep: enormh[k] = -ESCALE*||e_k||^2/2 (C-init for scaled scores), codebook
// scaled x512 -> fp8 e4m3 in MFMA B-fragment order:
// byte = (k>>4)*4096 + (ks>>1)*1024 + (lk*16+(k&15))*16 + (ks&1)*8 + (d&7)
// ---------------------------------------------------------------------------
__global__ __launch_bounds__(64) void vq_prep_kernel(
    const float* __restrict__ E, float* __restrict__ enormh,
    unsigned char* __restrict__ Ef8) {
  const int k = blockIdx.x;   // code
  const int t = threadIdx.x;  // dims 4t..4t+3
  const float4 v = *reinterpret_cast<const float4*>(&E[k * DIM + t * 4]);
  const int d0 = t * 4;
  const int ks = d0 >> 5;
  const int lk = (d0 >> 3) & 3;
  const int j = d0 & 7;  // 0 or 4
  const int lane16 = lk * 16 + (k & 15);
  const size_t byte = (size_t)((k >> 4) * 4096) + (size_t)((ks >> 1) * 1024) +
                      (size_t)(lane16 * 16) + (size_t)((ks & 1) * 8 + j);
  int p = __builtin_amdgcn_cvt_pk_fp8_f32(v.x * ESCALE, v.y * ESCALE, 0, 0);
  p = __builtin_amdgcn_cvt_pk_fp8_f32(v.z * ESCALE, v.w * ESCALE, p, 1);
  *reinterpret_cast<unsigned int*>(Ef8 + byte) = (unsigned int)p;
  float s = v.x * v.x + v.y * v.y + v.z * v.z + v.w * v.w;
#pragma unroll
  for (int off = 32; off >= 1; off >>= 1) s += __shfl_down(s, off);
  if (t == 0) enormh[k] = -0.5f * ESCALE * s;
}

__device__ inline i64 pack_fp8x8(const float4& a, const float4& b) {
  int lo = __builtin_amdgcn_cvt_pk_fp8_f32(a.x, a.y, 0, 0);
  lo = __builtin_amdgcn_cvt_pk_fp8_f32(a.z, a.w, lo, 1);
  int hi = __builtin_amdgcn_cvt_pk_fp8_f32(b.x, b.y, 0, 0);
  hi = __builtin_amdgcn_cvt_pk_fp8_f32(b.z, b.w, hi, 1);
  return ((i64)(unsigned int)hi << 32) | (i64)(unsigned int)lo;
}

// ---------------------------------------------------------------------------
// Fused main v14: barrier-free fp8 register pipeline at 4 waves/SIMD.
// 64 rows/block, 256 thr = 4 independent waves; wave w owns rows
// [w*16,w*16+16) x ALL 1024 codes (Af[8]=16 VGPR). 1024 blocks = 4 blocks/CU
// = 16 waves/CU: co-resident waves fill each other's L2-latency stalls.
// B + enorm stream L2->regs through named double buffers with a 2-tile-ahead
// prefetch window; no __syncthreads until the tiny epilogue tail.
// ---------------------------------------------------------------------------
__global__ __launch_bounds__(256, 4) void vq_fused_kernel(
    const float* __restrict__ X, const float* __restrict__ E,
    const unsigned char* __restrict__ Ef8, const float* __restrict__ enormh,
    float* __restrict__ outq, float* __restrict__ partials) {
  __shared__ int idxs[BM];
  __shared__ float lred[4];

  const int tid = threadIdx.x;
  const int w = tid >> 6;  // wave 0..3 -> rows w*16 .. w*16+15
  const int lane = tid & 63;
  const int lr = lane & 15;
  const int lk = lane >> 4;
  const int row0 = blockIdx.x * BM;

  // ---- A: 16 rows x 256 dims per wave, fp32 -> fp8 fragments (16 VGPRs)
  i64 Af[8];
  {
    const float* xrow = &X[(size_t)(row0 + w * 16 + lr) * DIM];
#pragma unroll
    for (int ks = 0; ks < 8; ++ks) {
      const int k0 = ks * 32 + lk * 8;
      const float4 a = *reinterpret_cast<const float4*>(&xrow[k0]);
      const float4 b = *reinterpret_cast<const float4*>(&xrow[k0 + 4]);
      Af[ks] = pack_fp8x8(a, b);
    }
  }

  float maxv[4];
  int mini[4];
#pragma unroll
  for (int i = 0; i < 4; ++i) { maxv[i] = -INFINITY; mini[i] = 0; }

  const char* efbase = reinterpret_cast<const char*>(Ef8) + lane * 16;

  // ---- named register double-buffer: tile = 4 x i64x2 (16 VGPRs each),
  // plus the tile's enorm value in the same prefetch window
  i64x2 B0[4], B1[4];
  float en0, en1;
#pragma unroll
  for (int p = 0; p < 4; ++p)
    B0[p] = *reinterpret_cast<const i64x2*>(efbase + p * 1024);
#pragma unroll
  for (int p = 0; p < 4; ++p)
    B1[p] = *reinterpret_cast<const i64x2*>(efbase + 4096 + p * 1024);
  en0 = enormh[lr];
  en1 = enormh[16 + lr];

#define COMPUTE_TILE(BUF)                                                    \
  {                                                                          \
    _Pragma("unroll") for (int p = 0; p < 4; ++p) {                          \
      acc = __builtin_amdgcn_mfma_f32_16x16x32_fp8_fp8(Af[2 * p], BUF[p][0], \
                                                       acc, 0, 0, 0);        \
      acc = __builtin_amdgcn_mfma_f32_16x16x32_fp8_fp8(                      \
          Af[2 * p + 1], BUF[p][1], acc, 0, 0, 0);                           \
    }                                                                        \
  }

#define RELOAD(BUF, EN, TILE)                                                \
  {                                                                          \
    const char* nsrc = efbase + (size_t)(TILE) * 4096;                       \
    _Pragma("unroll") for (int p = 0; p < 4; ++p) BUF[p] =                   \
        *reinterpret_cast<const i64x2*>(nsrc + p * 1024);                    \
    EN = enormh[(TILE) * 16 + lr];                                           \
  }

#pragma unroll
  for (int t = 0; t < NTILE; ++t) {
    f32x4 acc;
    if (t & 1) {
      acc[0] = en1; acc[1] = en1; acc[2] = en1; acc[3] = en1;
      COMPUTE_TILE(B1);
      if (t + 2 < NTILE) RELOAD(B1, en1, t + 2);
    } else {
      acc[0] = en0; acc[1] = en0; acc[2] = en0; acc[3] = en0;
      COMPUTE_TILE(B0);
      if (t + 2 < NTILE) RELOAD(B0, en0, t + 2);
    }
    const int code = t * 16 + lr;  // ascending per lane -> first occurrence
#pragma unroll
    for (int r = 0; r < 4; ++r) {
      const float s = acc[r];
      if (s > maxv[r]) { maxv[r] = s; mini[r] = code; }
    }
  }
#undef COMPUTE_TILE
#undef RELOAD

  // reduce across the 16 code-lanes (lr); max score, tie -> lower code
#pragma unroll
  for (int off = 1; off < 16; off <<= 1) {
#pragma unroll
    for (int r = 0; r < 4; ++r) {
      const float ov = __shfl_xor(maxv[r], off);
      const int oi = __shfl_xor(mini[r], off);
      if (ov > maxv[r] || (ov == maxv[r] && oi < mini[r])) {
        maxv[r] = ov; mini[r] = oi;
      }
    }
  }
  if (lr == 0) {
#pragma unroll
    for (int r = 0; r < 4; ++r) idxs[w * 16 + lk * 4 + r] = mini[r];
  }
  __syncthreads();

  // ---- fused epilogue: gather + STE + loss partial, exact fp32.
  // 4 threads per row, 64 dims each, coalesced float4.
  const int er = tid >> 2;  // row 0..63
  const int eq = tid & 3;
  const int code = idxs[er];
  const float* erow = &E[(size_t)code * DIM];
  const float* xrow = &X[(size_t)(row0 + er) * DIM];
  float* orow = &outq[(size_t)(row0 + er) * DIM];
  float lsum = 0.0f;
#pragma unroll
  for (int j = 0; j < 16; ++j) {
    const int d = j * 16 + eq * 4;
    const float4 e = *reinterpret_cast<const float4*>(&erow[d]);
    const float4 x = *reinterpret_cast<const float4*>(&xrow[d]);
    const float dx0 = e.x - x.x, dx1 = e.y - x.y;
    const float dx2 = e.z - x.z, dx3 = e.w - x.w;
    float4 o;
    o.x = x.x + dx0; o.y = x.y + dx1; o.z = x.z + dx2; o.w = x.w + dx3;
    *reinterpret_cast<float4*>(&orow[d]) = o;
    lsum += dx0 * dx0 + dx1 * dx1 + dx2 * dx2 + dx3 * dx3;
  }
#pragma unroll
  for (int off = 32; off >= 1; off >>= 1) lsum += __shfl_down(lsum, off);
  if (lane == 0) lred[w] = lsum;
  __syncthreads();
  if (tid == 0)
    partials[blockIdx.x] = lred[0] + lred[1] + lred[2] + lred[3];
}

// ---------------------------------------------------------------------------
// Deterministic loss reduction
// ---------------------------------------------------------------------------
__global__ __launch_bounds__(256) void vq_finalize_kernel(
    const float* __restrict__ partials, float* __restrict__ out_loss,
    int nparts, float inv_count) {
  const int tid = threadIdx.x;
  float s = 0.0f;
  for (int i = tid; i < nparts; i += 256) s += partials[i];
#pragma unroll
  for (int off = 32; off >= 1; off >>= 1) s += __shfl_down(s, off);
  __shared__ float w[4];
  if ((tid & 63) == 0) w[tid >> 6] = s;
  __syncthreads();
  if (tid == 0) {
    const float m = (w[0] + w[1] + w[2] + w[3]) * inv_count;
    out_loss[0] = m + 0.25f * m;  // q_latent + commitment * e_latent
  }
}

extern "C" void kernel_launch(void* const* d_in, const int* in_sizes, int n_in,
                              void* d_out, int out_size, void* d_ws,
                              size_t ws_size, hipStream_t stream) {
  const float* X = (const float*)d_in[0];  // [16,4096,256] fp32
  const float* E = (const float*)d_in[1];  // [1024,256] fp32
  float* out = (float*)d_out;              // [0]=loss, [1..]=quantized

  char* ws = (char*)d_ws;
  float* enormh = (float*)ws;                             // @0KB
  float* partials = (float*)(ws + 16 * 1024);             // @16KB (up to 4K)
  unsigned char* Ef8 = (unsigned char*)(ws + 48 * 1024);  // @48KB (256KB)

  const int nrows = in_sizes[0] / DIM;  // 65536
  const int nb_main = nrows / BM;       // 1024

  vq_prep_kernel<<<KCODES, 64, 0, stream>>>(E, enormh, Ef8);
  vq_fused_kernel<<<nb_main, 256, 0, stream>>>(X, E, Ef8, enormh, out + 1,
                                               partials);
  vq_finalize_kernel<<<1, 256, 0, stream>>>(partials, out, nb_main,
                                            1.0f / (float)in_sizes[0]);
}